// Round 2
// baseline (305.827 us; speedup 1.0000x reference)
//
#include <hip/hip_runtime.h>
#include <hip/hip_bf16.h>
#include <stdint.h>
#include <stddef.h>

// DCNv2 forward: B=4, H=W=96, C=256, F=256, K=9 (3x3, same, stride1, dil1), DG=1.
// R5 post-mortem: fused sampling+GEMM was FETCH-bound (313MB): N-tile=128 duplicated
//   sampling 2x and gathers half-used lines. REVERTED then.
// R7: chunk-XOR swizzle killed bank conflicts (6.19M -> 0) but dur flat at 64.5us ->
//   k_gemm is stage/barrier-stall-bound (T2-null-at-2phase regime). Swizzle kept.
// R8: retry the fusion with both R5 failure causes fixed:
//   - full-N tile (128M x 256N, 8 waves): sampling computed ONCE per px.
//   - corner offsets fixed across the 8 c-steps of each k -> corner rows stream
//     sequentially (full line use), xp (19.7MB) is L2/L3-resident.
//   k_sample + k_gemm (~120us, 340MB cols round-trip) -> single k_fused (~40us est).

namespace {
constexpr int H  = 96, W = 96, C = 256, F = 256;
constexpr int HP = 98;            // padded spatial dim (1-px zero halo)
constexpr int NP = 4 * 96 * 96;   // 36864 output pixels
constexpr int KC = 9 * 256;       // 2304 = GEMM K

constexpr int NB_PAD  = 4 * HP * HP / 8;  // 4802 blocks, 8 px each
constexpr int NB_OMW  = 9 * 32;           // 288
constexpr int NB_WT   = (KC / 64) * (F / 64);  // 144
constexpr int NB_ZERO = NP * 32 * 4 / 4096;    // 1152 (float4 x 256 thr)
}

typedef __attribute__((ext_vector_type(8))) short bf16x8;
typedef __attribute__((ext_vector_type(4))) float floatx4;

__device__ __forceinline__ void load_lds16(const void* g, void* l) {
  __builtin_amdgcn_global_load_lds((const __attribute__((address_space(1))) void*)g,
                                   (__attribute__((address_space(3))) void*)l,
                                   16, 0, 0);
}

__device__ __forceinline__ uint32_t pk2(float lo, float hi) {   // v_cvt_pk_bf16_f32 (RNE)
  __hip_bfloat162 t = __float22bfloat162_rn(float2{lo, hi});
  return *reinterpret_cast<uint32_t*>(&t);
}

__device__ __forceinline__ void acc8(uint4 v, float w, float* a) {
  a[0] += w * __uint_as_float(v.x << 16); a[1] += w * __uint_as_float(v.x & 0xffff0000u);
  a[2] += w * __uint_as_float(v.y << 16); a[3] += w * __uint_as_float(v.y & 0xffff0000u);
  a[4] += w * __uint_as_float(v.z << 16); a[5] += w * __uint_as_float(v.z & 0xffff0000u);
  a[6] += w * __uint_as_float(v.w << 16); a[7] += w * __uint_as_float(v.w & 0xffff0000u);
}

// ---------------- k_prep: pad + omw + wt + pOm-zero in one dispatch ----------------
__global__ __launch_bounds__(256) void k_prep(const float* __restrict__ x,
                                              const float* __restrict__ omk,
                                              const float* __restrict__ kern,
                                              uint4* __restrict__ xp4,
                                              __hip_bfloat16* __restrict__ wom,
                                              __hip_bfloat16* __restrict__ wt,
                                              float4* __restrict__ pOmz) {
  __shared__ float t[64][65];
  const int bi = blockIdx.x, tid = threadIdx.x;

  if (bi < NB_PAD) {                       // ---- pad: 8 px/block, 8 ch/thread ----
    const int sub = tid >> 5, cid = tid & 31;
    const int pp  = bi * 8 + sub;
    const int b   = pp / (HP * HP);
    const int r   = pp % (HP * HP);
    const int y   = r / HP, xq = r % HP;
    uint4 o = {0u, 0u, 0u, 0u};
    if (y >= 1 && y <= H && xq >= 1 && xq <= W) {
      const float* src = x + ((size_t)((b * H + (y - 1)) * W + (xq - 1))) * C + cid * 8;
      const float4 v0 = *(const float4*)src;
      const float4 v1 = *(const float4*)(src + 4);
      o.x = pk2(v0.x, v0.y); o.y = pk2(v0.z, v0.w);
      o.z = pk2(v1.x, v1.y); o.w = pk2(v1.z, v1.w);
    }
    xp4[(size_t)pp * 32 + cid] = o;
  } else if (bi < NB_PAD + NB_OMW) {       // ---- omw: [9*256][27] -> [32][2304] ----
    const int i  = bi - NB_PAD;
    const int kk = i / 32, oc = i % 32;
    float v = (oc < 27) ? omk[(size_t)(kk * 256 + tid) * 27 + oc] : 0.f;
    wom[(size_t)oc * KC + kk * 256 + tid] = __float2bfloat16(v);
  } else if (bi < NB_PAD + NB_OMW + NB_WT) {  // ---- wt: [KC][F] -> [F][KC] bf16 ----
    const int j   = bi - NB_PAD - NB_OMW;
    const int kc0 = (j % (KC / 64)) * 64, f0 = (j / (KC / 64)) * 64;
    const int rr = tid >> 6, cc = tid & 63;
#pragma unroll
    for (int i = 0; i < 16; ++i)
      t[rr * 16 + i][cc] = kern[(size_t)(kc0 + rr * 16 + i) * F + f0 + cc];
    __syncthreads();
#pragma unroll
    for (int i = 0; i < 16; ++i) {
      const int frow = rr * 16 + i;
      wt[(size_t)(f0 + frow) * KC + kc0 + cc] = __float2bfloat16(t[cc][frow]);
    }
  } else {                                 // ---- pOm zero ----
    const int j = bi - NB_PAD - NB_OMW - NB_WT;
    pOmz[(size_t)j * 256 + tid] = (float4){0.f, 0.f, 0.f, 0.f};
  }
}

// ---------------- k_omgemm: implicit-im2col MFMA GEMM, 128(M)x32(N), split-K x6 ----------------
__global__ __launch_bounds__(256) void k_omgemm(const __hip_bfloat16* __restrict__ xp,
                                                const __hip_bfloat16* __restrict__ wom,
                                                float* __restrict__ pOm) {
  __shared__ __align__(16) char lds[10240];
  const int tid  = threadIdx.x;
  const int m0   = blockIdx.x * 128;
  const int s    = blockIdx.y;
  const int lane = tid & 63, wave = tid >> 6;
  const int quad = lane >> 4, l16 = lane & 15;

  const int kp = (tid & 3) ^ ((tid >> 3) & 3);
  const __hip_bfloat16* abase[2];
#pragma unroll
  for (int j = 0; j < 2; ++j) {
    const int row = (tid >> 2) + j * 64;
    const int p = m0 + row;
    const int b = p / (H * W);
    const int hw = p % (H * W);
    const int h = hw / W, w = hw % W;
    abase[j] = xp + ((size_t)(b * HP + h) * HP + w) * C + kp * 8;
  }
  const __hip_bfloat16* bbase = wom + (size_t)(tid >> 2) * KC + kp * 8;

  floatx4 acc[2][2];
#pragma unroll
  for (int i = 0; i < 2; ++i)
#pragma unroll
    for (int j = 0; j < 2; ++j) acc[i][j] = (floatx4){0.f, 0.f, 0.f, 0.f};

  const int swq = (quad ^ ((l16 >> 1) & 3)) * 16;

  const int kbeg = s * 384;
#pragma unroll 1
  for (int k0 = kbeg; k0 < kbeg + 384; k0 += 32) {
    const int kk = k0 >> 8;
    const int c0 = k0 & 255;
    const int kh = kk / 3, kw = kk % 3;
    const int aoff = (kh * HP + kw) * C + c0;

    __syncthreads();
    load_lds16(abase[0] + aoff, &lds[tid * 16]);
    load_lds16(abase[1] + aoff, &lds[4096 + tid * 16]);
    if (tid < 128) load_lds16(bbase + k0, &lds[8192 + tid * 16]);
    __syncthreads();

    bf16x8 af[2], bfr[2];
#pragma unroll
    for (int mt = 0; mt < 2; ++mt)
      af[mt] = *(const bf16x8*)&lds[(wave * 32 + mt * 16 + l16) * 64 + swq];
#pragma unroll
    for (int nt = 0; nt < 2; ++nt)
      bfr[nt] = *(const bf16x8*)&lds[8192 + (nt * 16 + l16) * 64 + swq];
#pragma unroll
    for (int mt = 0; mt < 2; ++mt)
#pragma unroll
      for (int nt = 0; nt < 2; ++nt)
        acc[mt][nt] = __builtin_amdgcn_mfma_f32_16x16x32_bf16(af[mt], bfr[nt], acc[mt][nt], 0, 0, 0);
  }

#pragma unroll
  for (int mt = 0; mt < 2; ++mt)
#pragma unroll
    for (int nt = 0; nt < 2; ++nt) {
      const int gm = m0 + wave * 32 + mt * 16 + quad * 4;
      const int gn = nt * 16 + l16;
#pragma unroll
      for (int r = 0; r < 4; ++r)
        __hip_atomic_fetch_add(&pOm[(size_t)(gm + r) * 32 + gn], acc[mt][nt][r],
                               __ATOMIC_RELAXED, __HIP_MEMORY_SCOPE_AGENT);
    }
}

// ---------------- k_fused: sampling fused into A-staging of the main GEMM ----------------
// 128(M) x 256(N=full F) tile, 512 thr = 8 waves (2M x 4N), wave tile 64x64.
// Per K-step (32 ch of kernel-point kk): each thread gathers 4 corner uint4 for its
// (px = tid>>2, 8-ch chunk = tid&3), weighted-sums (mask folded), packs bf16,
// ds_writes the chunk-XOR-swizzled A tile. B staged via global_load_lds from wt.
__global__ __launch_bounds__(512) void k_fused(const uint4* __restrict__ xp4,
                                               const __hip_bfloat16* __restrict__ wt,
                                               const float* __restrict__ pOm,
                                               const float* __restrict__ omb,
                                               const float* __restrict__ bias,
                                               float* __restrict__ out) {
  __shared__ __align__(16) char lds[28672];   // A [128][32]bf16 @0 (8KB), B [256][32] @8192 (16KB),
  float2* s_ow = (float2*)&lds[24576];        // s_ow [128][4] float2 @24576 (4KB)

  const int tid  = threadIdx.x;
  const int m0   = blockIdx.x * 128;
  const int lane = tid & 63, wave = tid >> 6;
  const int wm = wave >> 2, wn = wave & 3;    // 2M x 4N waves of 64x64
  const int quad = lane >> 4, l16 = lane & 15;
  const int swq  = (quad ^ ((l16 >> 1) & 3)) * 16;

  // sampling / setup role: px = tid>>2, chunk / corner = tid&3
  const int spx = tid >> 2, sq = tid & 3;
  const int p_my  = m0 + spx;
  const int b_my  = p_my / (H * W);
  const int hw_my = p_my % (H * W);
  const int h_my  = hw_my / W, w_my = hw_my % W;

  // B staging role: 2 rounds of 128 rows
  const int bkp = (tid & 3) ^ ((tid >> 3) & 3);
  const __hip_bfloat16* bsrc0 = wt + (size_t)(tid >> 2) * KC + bkp * 8;
  const __hip_bfloat16* bsrc1 = bsrc0 + (size_t)128 * KC;

  floatx4 acc[4][4];
#pragma unroll
  for (int i = 0; i < 4; ++i)
#pragma unroll
    for (int j = 0; j < 4; ++j) acc[i][j] = (floatx4){0.f, 0.f, 0.f, 0.f};

#pragma unroll 1
  for (int kk = 0; kk < 9; ++kk) {
    // ---- per-k corner offsets/weights: 512 thr = 128 px x 4 corners, one each ----
    {
      const float dy = omb[2 * kk]     + pOm[(size_t)p_my * 32 + 2 * kk];
      const float dx = omb[2 * kk + 1] + pOm[(size_t)p_my * 32 + 2 * kk + 1];
      const float mv = omb[18 + kk]    + pOm[(size_t)p_my * 32 + 18 + kk];
      const float m  = 2.f / (1.f + __expf(-mv));
      const float sy = (float)(h_my - 1 + kk / 3) + dy;
      const float sx = (float)(w_my - 1 + kk % 3) + dx;
      const float y0f = floorf(sy), x0f = floorf(sx);
      const float fy = sy - y0f, fx = sx - x0f;
      const int y0 = (int)y0f, x0 = (int)x0f;
      const int dy2 = sq >> 1, dx2 = sq & 1;
      const int yi = y0 + dy2, xi = x0 + dx2;
      const bool valid = (yi >= 0) & (yi < H) & (xi >= 0) & (xi < W);
      const float wgt = valid ? (dy2 ? fy : 1.f - fy) * (dx2 ? fx : 1.f - fx) * m : 0.f;
      const int yc = min(max(yi + 1, 0), HP - 1);
      const int xc = min(max(xi + 1, 0), HP - 1);
      const int off = ((b_my * HP + yc) * HP + xc) * 32;   // uint4 units
      s_ow[spx * 4 + sq] = float2{__int_as_float(off), wgt};
    }
    __syncthreads();

    // my px's 4 corners -> regs (fixed for the 8 c-steps of this k)
    const float4 ow01 = *(const float4*)&s_ow[spx * 4 + 0];
    const float4 ow23 = *(const float4*)&s_ow[spx * 4 + 2];
    const uint4* p0 = xp4 + __float_as_int(ow01.x) + sq;
    const uint4* p1 = xp4 + __float_as_int(ow01.z) + sq;
    const uint4* p2 = xp4 + __float_as_int(ow23.x) + sq;
    const uint4* p3 = xp4 + __float_as_int(ow23.z) + sq;
    const float w0 = ow01.y, w1 = ow01.w, w2 = ow23.y, w3 = ow23.w;

#pragma unroll 1
    for (int c = 0; c < 8; ++c) {
      // stage B tile (256 rows x 32 ch) for k0 = kk*256 + c*32
      load_lds16(bsrc0 + kk * 256 + c * 32, &lds[8192 + tid * 16]);
      load_lds16(bsrc1 + kk * 256 + c * 32, &lds[16384 + tid * 16]);

      // sample my (px, 8-ch chunk) of the A tile
      const uint4 g0 = p0[c * 4], g1 = p1[c * 4], g2 = p2[c * 4], g3 = p3[c * 4];
      float a[8] = {0.f, 0.f, 0.f, 0.f, 0.f, 0.f, 0.f, 0.f};
      acc8(g0, w0, a); acc8(g1, w1, a); acc8(g2, w2, a); acc8(g3, w3, a);
      uint4 o;
      o.x = pk2(a[0], a[1]); o.y = pk2(a[2], a[3]);
      o.z = pk2(a[4], a[5]); o.w = pk2(a[6], a[7]);
      *(uint4*)&lds[spx * 64 + (sq ^ ((spx >> 1) & 3)) * 16] = o;

      __syncthreads();   // drains vmcnt (B loads) + lgkm (A writes)

      bf16x8 af[4], bfr[4];
#pragma unroll
      for (int mt = 0; mt < 4; ++mt)
        af[mt] = *(const bf16x8*)&lds[(wm * 64 + mt * 16 + l16) * 64 + swq];
#pragma unroll
      for (int nt = 0; nt < 4; ++nt)
        bfr[nt] = *(const bf16x8*)&lds[8192 + (wn * 64 + nt * 16 + l16) * 64 + swq];
#pragma unroll
      for (int mt = 0; mt < 4; ++mt)
#pragma unroll
        for (int nt = 0; nt < 4; ++nt)
          acc[mt][nt] = __builtin_amdgcn_mfma_f32_16x16x32_bf16(af[mt], bfr[nt], acc[mt][nt], 0, 0, 0);

      __syncthreads();   // frag reads done before next c-step overwrites tiles
    }
  }

#pragma unroll
  for (int mt = 0; mt < 4; ++mt) {
#pragma unroll
    for (int nt = 0; nt < 4; ++nt) {
      const int gm = m0 + wm * 64 + mt * 16 + quad * 4;
      const int gn = wn * 64 + nt * 16 + l16;
      const float bs = bias[gn];
#pragma unroll
      for (int r = 0; r < 4; ++r)
        out[(size_t)(gm + r) * F + gn] = acc[mt][nt][r] + bs;
    }
  }
}

extern "C" void kernel_launch(void* const* d_in, const int* in_sizes, int n_in,
                              void* d_out, int out_size, void* d_ws, size_t ws_size,
                              hipStream_t stream) {
  const float* x    = (const float*)d_in[0];   // [4,96,96,256]
  const float* omk  = (const float*)d_in[1];   // [3,3,256,27]
  const float* omb  = (const float*)d_in[2];   // [27]
  const float* kern = (const float*)d_in[3];   // [2304,256]
  const float* bias = (const float*)d_in[4];   // [256]
  float* out = (float*)d_out;                  // [4,96,96,256]

  char* ws = (char*)d_ws;
  size_t off = 0;
  __hip_bfloat16* wt   = (__hip_bfloat16*)(ws + off); off += (size_t)F * KC * 2;           // 1,179,648
  __hip_bfloat16* xp   = (__hip_bfloat16*)(ws + off); off += (size_t)4 * HP * HP * C * 2;  // 19,668,992
  __hip_bfloat16* wom  = (__hip_bfloat16*)(ws + off); off += (size_t)32 * KC * 2;          // 147,456
  float*          pOm  = (float*)(ws + off);          off += (size_t)NP * 32 * 4;          // 4,718,592

  k_prep  <<<dim3(NB_PAD + NB_OMW + NB_WT + NB_ZERO), 256, 0, stream>>>(
      x, omk, kern, (uint4*)xp, wom, wt, (float4*)pOm);
  k_omgemm<<<dim3(NP / 128, 6), 256, 0, stream>>>(xp, wom, pOm);
  k_fused <<<dim3(NP / 128),    512, 0, stream>>>((const uint4*)xp, wt, pOm, omb, bias, out);
}

// Round 3
// 221.988 us; speedup vs baseline: 1.3777x; 1.3777x over previous
//
#include <hip/hip_runtime.h>
#include <hip/hip_bf16.h>
#include <stdint.h>
#include <stddef.h>

// DCNv2 forward: B=4, H=W=96, C=256, F=256, K=9 (3x3, same, stride1, dil1), DG=1.
// R5/R8 post-mortem: fused sampling+GEMM fails twice: R5 FETCH-bound (N-dup, half lines),
//   R8 latency/occupancy-bound (288 blocks = 1.1/CU, lockstep barriers) + XCD L2 thrash
//   (FETCH 168MB = 8.5x xp). REVERTED to split pipeline.
// R7: chunk-XOR swizzle killed k_gemm bank conflicts (6.19M->0), dur flat -> stall-bound.
// R9: three targeted fixes on the split pipeline:
//   (a) k_gemm + k_omgemm: 1-phase -> 2-phase double-buffered LDS (T3-minimum: one
//       barrier/iter, stage(t+1) issued after barrier, MFMA(t) covers load latency).
//   (b) k_sample + k_omgemm: XCD-contiguous block swizzle so each XCD's xp gather
//       footprint (~2.5MB) fits its 4MB L2 (R8 counter: round-robin = 8.5x refetch).
//       Both kernels use the SAME px partition so each XCD keeps one xp slice warm.

namespace {
constexpr int H  = 96, W = 96, C = 256, F = 256;
constexpr int HP = 98;            // padded spatial dim (1-px zero halo)
constexpr int NP = 4 * 96 * 96;   // 36864 output pixels
constexpr int KC = 9 * 256;       // 2304 = GEMM K

constexpr int NB_PAD  = 4 * HP * HP / 8;  // 4802 blocks, 8 px each
constexpr int NB_OMW  = 9 * 32;           // 288
constexpr int NB_WT   = (KC / 64) * (F / 64);  // 144
constexpr int NB_ZERO = NP * 32 * 4 / 4096;    // 1152 (float4 x 256 thr)
}

typedef __attribute__((ext_vector_type(8))) short bf16x8;
typedef __attribute__((ext_vector_type(4))) float floatx4;

__device__ __forceinline__ void load_lds16(const void* g, void* l) {
  __builtin_amdgcn_global_load_lds((const __attribute__((address_space(1))) void*)g,
                                   (__attribute__((address_space(3))) void*)l,
                                   16, 0, 0);
}

__device__ __forceinline__ uint32_t pk2(float lo, float hi) {   // v_cvt_pk_bf16_f32 (RNE)
  __hip_bfloat162 t = __float22bfloat162_rn(float2{lo, hi});
  return *reinterpret_cast<uint32_t*>(&t);
}

__device__ __forceinline__ void acc8(uint4 v, float w, float* a) {
  a[0] += w * __uint_as_float(v.x << 16); a[1] += w * __uint_as_float(v.x & 0xffff0000u);
  a[2] += w * __uint_as_float(v.y << 16); a[3] += w * __uint_as_float(v.y & 0xffff0000u);
  a[4] += w * __uint_as_float(v.z << 16); a[5] += w * __uint_as_float(v.z & 0xffff0000u);
  a[6] += w * __uint_as_float(v.w << 16); a[7] += w * __uint_as_float(v.w & 0xffff0000u);
}

// ---------------- k_prep: pad + omw + wt + pOm-zero in one dispatch ----------------
__global__ __launch_bounds__(256) void k_prep(const float* __restrict__ x,
                                              const float* __restrict__ omk,
                                              const float* __restrict__ kern,
                                              uint4* __restrict__ xp4,
                                              __hip_bfloat16* __restrict__ wom,
                                              __hip_bfloat16* __restrict__ wt,
                                              float4* __restrict__ pOmz) {
  __shared__ float t[64][65];
  const int bi = blockIdx.x, tid = threadIdx.x;

  if (bi < NB_PAD) {                       // ---- pad: 8 px/block, 8 ch/thread ----
    const int sub = tid >> 5, cid = tid & 31;
    const int pp  = bi * 8 + sub;
    const int b   = pp / (HP * HP);
    const int r   = pp % (HP * HP);
    const int y   = r / HP, xq = r % HP;
    uint4 o = {0u, 0u, 0u, 0u};
    if (y >= 1 && y <= H && xq >= 1 && xq <= W) {
      const float* src = x + ((size_t)((b * H + (y - 1)) * W + (xq - 1))) * C + cid * 8;
      const float4 v0 = *(const float4*)src;
      const float4 v1 = *(const float4*)(src + 4);
      o.x = pk2(v0.x, v0.y); o.y = pk2(v0.z, v0.w);
      o.z = pk2(v1.x, v1.y); o.w = pk2(v1.z, v1.w);
    }
    xp4[(size_t)pp * 32 + cid] = o;
  } else if (bi < NB_PAD + NB_OMW) {       // ---- omw: [9*256][27] -> [32][2304] ----
    const int i  = bi - NB_PAD;
    const int kk = i / 32, oc = i % 32;
    float v = (oc < 27) ? omk[(size_t)(kk * 256 + tid) * 27 + oc] : 0.f;
    wom[(size_t)oc * KC + kk * 256 + tid] = __float2bfloat16(v);
  } else if (bi < NB_PAD + NB_OMW + NB_WT) {  // ---- wt: [KC][F] -> [F][KC] bf16 ----
    const int j   = bi - NB_PAD - NB_OMW;
    const int kc0 = (j % (KC / 64)) * 64, f0 = (j / (KC / 64)) * 64;
    const int rr = tid >> 6, cc = tid & 63;
#pragma unroll
    for (int i = 0; i < 16; ++i)
      t[rr * 16 + i][cc] = kern[(size_t)(kc0 + rr * 16 + i) * F + f0 + cc];
    __syncthreads();
#pragma unroll
    for (int i = 0; i < 16; ++i) {
      const int frow = rr * 16 + i;
      wt[(size_t)(f0 + frow) * KC + kc0 + cc] = __float2bfloat16(t[cc][frow]);
    }
  } else {                                 // ---- pOm zero ----
    const int j = bi - NB_PAD - NB_OMW - NB_WT;
    pOmz[(size_t)j * 256 + tid] = (float4){0.f, 0.f, 0.f, 0.f};
  }
}

// ---------------- k_omgemm: implicit-im2col MFMA GEMM, 128(M)x32(N), split-K x6 ----------------
// R9: 2-phase double-buffer + XCD-contiguous m-tile swizzle (36 tiles = 4608 px per XCD,
// aligned with k_sample's partition).
__global__ __launch_bounds__(256) void k_omgemm(const __hip_bfloat16* __restrict__ xp,
                                                const __hip_bfloat16* __restrict__ wom,
                                                float* __restrict__ pOm) {
  __shared__ __align__(16) char lds[20480];   // 2 x {A [128][32] 8KB, B [32][32] 2KB}
  const int tid  = threadIdx.x;
  const int xr   = blockIdx.x;
  const int xs   = (xr & 7) * 36 + (xr >> 3);     // XCD-contiguous
  const int m0   = xs * 128;
  const int s    = blockIdx.y;
  const int lane = tid & 63, wave = tid >> 6;
  const int quad = lane >> 4, l16 = lane & 15;

  const int kp = (tid & 3) ^ ((tid >> 3) & 3);
  const __hip_bfloat16* abase[2];
#pragma unroll
  for (int j = 0; j < 2; ++j) {
    const int row = (tid >> 2) + j * 64;
    const int p = m0 + row;
    const int b = p / (H * W);
    const int hw = p % (H * W);
    const int h = hw / W, w = hw % W;
    abase[j] = xp + ((size_t)(b * HP + h) * HP + w) * C + kp * 8;
  }
  const __hip_bfloat16* bbase = wom + (size_t)(tid >> 2) * KC + kp * 8;

  auto stage = [&](int buf, int k0) {
    const int kk = k0 >> 8, c0 = k0 & 255;
    const int aoff = ((kk / 3) * HP + (kk % 3)) * C + c0;
    char* base = &lds[buf * 10240];
    load_lds16(abase[0] + aoff, base + tid * 16);
    load_lds16(abase[1] + aoff, base + 4096 + tid * 16);
    if (tid < 128) load_lds16(bbase + k0, base + 8192 + tid * 16);
  };

  floatx4 acc[2][2];
#pragma unroll
  for (int i = 0; i < 2; ++i)
#pragma unroll
    for (int j = 0; j < 2; ++j) acc[i][j] = (floatx4){0.f, 0.f, 0.f, 0.f};

  const int swq = (quad ^ ((l16 >> 1) & 3)) * 16;

  const int kbeg = s * 384, kend = kbeg + 384;
  stage(0, kbeg);
  int cur = 0;
#pragma unroll 1
  for (int k0 = kbeg; k0 < kend; k0 += 32) {
    __syncthreads();                       // drains stage issued last iter (or prologue)
    if (k0 + 32 < kend) stage(cur ^ 1, k0 + 32);
    const char* base = &lds[cur * 10240];

    bf16x8 af[2], bfr[2];
#pragma unroll
    for (int mt = 0; mt < 2; ++mt)
      af[mt] = *(const bf16x8*)&base[(wave * 32 + mt * 16 + l16) * 64 + swq];
#pragma unroll
    for (int nt = 0; nt < 2; ++nt)
      bfr[nt] = *(const bf16x8*)&base[8192 + (nt * 16 + l16) * 64 + swq];
#pragma unroll
    for (int mt = 0; mt < 2; ++mt)
#pragma unroll
      for (int nt = 0; nt < 2; ++nt)
        acc[mt][nt] = __builtin_amdgcn_mfma_f32_16x16x32_bf16(af[mt], bfr[nt], acc[mt][nt], 0, 0, 0);
    cur ^= 1;
  }

#pragma unroll
  for (int mt = 0; mt < 2; ++mt)
#pragma unroll
    for (int nt = 0; nt < 2; ++nt) {
      const int gm = m0 + wave * 32 + mt * 16 + quad * 4;
      const int gn = nt * 16 + l16;
#pragma unroll
      for (int r = 0; r < 4; ++r)
        __hip_atomic_fetch_add(&pOm[(size_t)(gm + r) * 32 + gn], acc[mt][nt][r],
                               __ATOMIC_RELAXED, __HIP_MEMORY_SCOPE_AGENT);
    }
}

// ---------------- k_sample: 8 px/block, 8 ch/thread via uint4 full-line gathers ----------------
// R9: XCD-contiguous block swizzle -> each XCD gathers from a ~2.5MB xp slice (L2-resident).
__global__ __launch_bounds__(256) void k_sample(const uint4* __restrict__ xp4,
                                                const float* __restrict__ pOm,
                                                const float* __restrict__ om_bias,
                                                uint4* __restrict__ cols4) {
  __shared__ float2 s_ow[8][9][4];   // per (px,k,corner): {uint4-offset, weight*mask}

  const int tid = threadIdx.x;
  const int sub = tid >> 5, cid = tid & 31;     // px-in-block, 8-ch unit
  const int bs  = (blockIdx.x & 7) * 576 + (blockIdx.x >> 3);   // XCD-contiguous

  if (tid < 72) {                               // setup: 8 px x 9 k
    const int ps = tid / 9, k = tid % 9;
    const int p  = bs * 8 + ps;
    const int b  = p / (H * W);
    const int hw = p % (H * W);
    const int h = hw / W, w = hw % W;
    const float dy = om_bias[2 * k]     + pOm[(size_t)p * 32 + 2 * k];
    const float dx = om_bias[2 * k + 1] + pOm[(size_t)p * 32 + 2 * k + 1];
    const float mv = om_bias[18 + k]    + pOm[(size_t)p * 32 + 18 + k];
    const float m  = 2.f / (1.f + __expf(-mv));
    const float sy = (float)(h - 1 + k / 3) + dy;
    const float sx = (float)(w - 1 + k % 3) + dx;
    const float y0f = floorf(sy), x0f = floorf(sx);
    const float fy = sy - y0f, fx = sx - x0f;
    const int y0 = (int)y0f, x0 = (int)x0f;
#pragma unroll
    for (int c2 = 0; c2 < 4; ++c2) {
      const int dy2 = c2 >> 1, dx2 = c2 & 1;
      const int yi = y0 + dy2, xi = x0 + dx2;
      const bool valid = (yi >= 0) & (yi < H) & (xi >= 0) & (xi < W);
      const float wgt = valid ? (dy2 ? fy : 1.f - fy) * (dx2 ? fx : 1.f - fx) * m : 0.f;
      const int yc = min(max(yi + 1, 0), HP - 1);
      const int xc = min(max(xi + 1, 0), HP - 1);
      const int off = ((b * HP + yc) * HP + xc) * 32;   // uint4 units
      s_ow[ps][k][c2] = float2{__int_as_float(off), wgt};
    }
  }
  __syncthreads();

  const int p = bs * 8 + sub;
  uint4* __restrict__ ob = cols4 + (size_t)p * 288 + cid;   // KC bf16 = 288 uint4/row

#pragma unroll 1
  for (int k = 0; k < 9; ++k) {
    const float2 ow0 = s_ow[sub][k][0], ow1 = s_ow[sub][k][1];
    const float2 ow2 = s_ow[sub][k][2], ow3 = s_ow[sub][k][3];
    float a[8] = {0.f, 0.f, 0.f, 0.f, 0.f, 0.f, 0.f, 0.f};
    acc8(xp4[(size_t)__float_as_int(ow0.x) + cid], ow0.y, a);
    acc8(xp4[(size_t)__float_as_int(ow1.x) + cid], ow1.y, a);
    acc8(xp4[(size_t)__float_as_int(ow2.x) + cid], ow2.y, a);
    acc8(xp4[(size_t)__float_as_int(ow3.x) + cid], ow3.y, a);
    uint4 o;
    o.x = pk2(a[0], a[1]); o.y = pk2(a[2], a[3]);
    o.z = pk2(a[4], a[5]); o.w = pk2(a[6], a[7]);
    ob[k * 32] = o;
  }
}

// ---------------- k_gemm: bf16 MFMA GEMM, 96(M) x 128(N), 2-phase double-buffer ----------------
__global__ __launch_bounds__(256) void k_gemm(const __hip_bfloat16* __restrict__ A,
                                              const __hip_bfloat16* __restrict__ Bt,
                                              const float* __restrict__ bias,
                                              float* __restrict__ out) {
  __shared__ __align__(16) char lds[28672];   // 2 x {A [96][32] 6KB @0, B [128][32] 8KB @6144}

  const int tid  = threadIdx.x;
  const int m0   = blockIdx.x * 96;
  const int n0   = blockIdx.y * 128;
  const int lane = tid & 63, wave = tid >> 6;
  const int wm = wave & 1, wn = wave >> 1;    // wave = 48M x 64N
  const int quad = lane >> 4, l16 = lane & 15;

  const int row = tid >> 2, kp = (tid & 3) ^ ((tid >> 3) & 3);
  const __hip_bfloat16* a0 = A  + (size_t)(m0 + row) * KC + kp * 8;
  const __hip_bfloat16* a1 = A  + (size_t)(m0 + 64 + row) * KC + kp * 8;   // tid<128
  const __hip_bfloat16* b0 = Bt + (size_t)(n0 + row) * KC + kp * 8;
  const __hip_bfloat16* b1 = Bt + (size_t)(n0 + 64 + row) * KC + kp * 8;

  auto stage = [&](int buf, int k0) {
    char* base = &lds[buf * 14336];
    load_lds16(a0 + k0, base + tid * 16);
    if (tid < 128) load_lds16(a1 + k0, base + 4096 + tid * 16);
    load_lds16(b0 + k0, base + 6144 + tid * 16);
    load_lds16(b1 + k0, base + 10240 + tid * 16);
  };

  floatx4 acc[3][4];
#pragma unroll
  for (int i = 0; i < 3; ++i)
#pragma unroll
    for (int j = 0; j < 4; ++j) acc[i][j] = (floatx4){0.f, 0.f, 0.f, 0.f};

  const int swq = (quad ^ ((l16 >> 1) & 3)) * 16;

  stage(0, 0);
  int cur = 0;
#pragma unroll 1
  for (int k0 = 0; k0 < KC; k0 += 32) {
    __syncthreads();                       // drains stage issued last iter (or prologue)
    if (k0 + 32 < KC) stage(cur ^ 1, k0 + 32);
    const char* base = &lds[cur * 14336];

    bf16x8 af[3], bfr[4];
#pragma unroll
    for (int mt = 0; mt < 3; ++mt)
      af[mt] = *(const bf16x8*)&base[(wm * 48 + mt * 16 + l16) * 64 + swq];
#pragma unroll
    for (int nt = 0; nt < 4; ++nt)
      bfr[nt] = *(const bf16x8*)&base[6144 + (wn * 64 + nt * 16 + l16) * 64 + swq];
#pragma unroll
    for (int mt = 0; mt < 3; ++mt)
#pragma unroll
      for (int nt = 0; nt < 4; ++nt)
        acc[mt][nt] = __builtin_amdgcn_mfma_f32_16x16x32_bf16(af[mt], bfr[nt], acc[mt][nt], 0, 0, 0);
    cur ^= 1;
  }

#pragma unroll
  for (int mt = 0; mt < 3; ++mt) {
#pragma unroll
    for (int nt = 0; nt < 4; ++nt) {
      const int gm = m0 + wm * 48 + mt * 16 + quad * 4;
      const int gn = n0 + wn * 64 + nt * 16 + l16;
      const float bs = bias[gn];
#pragma unroll
      for (int r = 0; r < 4; ++r)
        out[(size_t)(gm + r) * F + gn] = acc[mt][nt][r] + bs;
    }
  }
}

extern "C" void kernel_launch(void* const* d_in, const int* in_sizes, int n_in,
                              void* d_out, int out_size, void* d_ws, size_t ws_size,
                              hipStream_t stream) {
  const float* x    = (const float*)d_in[0];   // [4,96,96,256]
  const float* omk  = (const float*)d_in[1];   // [3,3,256,27]
  const float* omb  = (const float*)d_in[2];   // [27]
  const float* kern = (const float*)d_in[3];   // [2304,256]
  const float* bias = (const float*)d_in[4];   // [256]
  float* out = (float*)d_out;                  // [4,96,96,256]

  char* ws = (char*)d_ws;
  size_t off = 0;
  __hip_bfloat16* wt   = (__hip_bfloat16*)(ws + off); off += (size_t)F * KC * 2;           // 1,179,648
  __hip_bfloat16* xp   = (__hip_bfloat16*)(ws + off); off += (size_t)4 * HP * HP * C * 2;  // 19,668,992
  __hip_bfloat16* wom  = (__hip_bfloat16*)(ws + off); off += (size_t)32 * KC * 2;          // 147,456
  float*          pOm  = (float*)(ws + off);          off += (size_t)NP * 32 * 4;          // 4,718,592
  __hip_bfloat16* cols = (__hip_bfloat16*)(ws + off);                                      // 169,869,312

  k_prep  <<<dim3(NB_PAD + NB_OMW + NB_WT + NB_ZERO), 256, 0, stream>>>(
      x, omk, kern, (uint4*)xp, wom, wt, (float4*)pOm);
  k_omgemm<<<dim3(NP / 128, 6),      256, 0, stream>>>(xp, wom, pOm);
  k_sample<<<dim3(NP / 8),           256, 0, stream>>>((const uint4*)xp, pOm, omb, (uint4*)cols);
  k_gemm  <<<dim3(NP / 96, F / 128), 256, 0, stream>>>(cols, wt, bias, out);
}